// Round 9
// baseline (273.729 us; speedup 1.0000x reference)
//
#include <hip/hip_runtime.h>
#include <math.h>

#define N0 200000
#define N1 1024
#define N2 256
#define N3 32
#define NE0 2048000
#define NE1 262144
#define NE2 8192
#define BATCH 32
#define NCLS 10
#define NB 4            // src-range buckets for gather0 (XCD L2 partitioning)
#define SRC_PER_B 50000 // N0 / NB
#define G0_BLOCKS (N1 * NB)

typedef _Float16 h2 __attribute__((ext_vector_type(2)));
typedef _Float16 h8 __attribute__((ext_vector_type(8)));

__device__ __forceinline__ int lower_bound_i(const int* __restrict__ a, int n, int key) {
    int lo = 0, hi = n;
    while (lo < hi) {
        int mid = (lo + hi) >> 1;
        if (a[mid] < key) lo = mid + 1; else hi = mid;
    }
    return lo;
}

// x (32, 200000) fp32 -> xt (200000, 32) fp16 rows (64 B each), LDS tiled.
__global__ __launch_bounds__(256) void k_transpose(const float* __restrict__ x,
                                                   h2* __restrict__ xt) {
    __shared__ float tile[32][65];
    const int col0 = blockIdx.x * 64;
    const int tid = threadIdx.x;
    const int c = tid & 63, r0 = tid >> 6;       // 4 row-lanes
    #pragma unroll
    for (int r = r0; r < 32; r += 4) {
        int col = col0 + c;
        tile[r][c] = (col < N0) ? x[r * N0 + col] : 0.f;
    }
    __syncthreads();
    const int bb = (tid & 15) * 2, c0 = tid >> 4; // 16 col-lanes, 2 batch rows/thread
    #pragma unroll
    for (int cc = c0; cc < 64; cc += 16) {
        int col = col0 + cc;
        if (col < N0) {
            h2 v;
            v[0] = (_Float16)tile[bb][cc];
            v[1] = (_Float16)tile[bb + 1][cc];
            xt[col * 16 + (bb >> 1)] = v;
        }
    }
}

// Stable 4-way partition of each dst-segment's src list by src bucket.
// Inline binary search for segment bounds (overlapped across 1024 blocks).
// Ballot-popcount counting (no atomics), ballot-rank stable scatter.
// Block 0 thread 0 also zeroes the gather0 completion counter (runs before
// k_gather0s in stream order each replay).
__global__ __launch_bounds__(256) void k_partition(const int* __restrict__ src,
                                                   const int* __restrict__ dst,
                                                   int* __restrict__ esrc,
                                                   int* __restrict__ bstart,
                                                   int* __restrict__ gcnt) {
    const int n = blockIdx.x;
    const int tid = threadIdx.x;
    if (n == 0 && tid == 0) *gcnt = 0;
    const int e0 = lower_bound_i(dst, NE0, n);
    const int e1 = lower_bound_i(dst, NE0, n + 1);
    const int len = e1 - e0;
    const int wave = tid >> 6, lane = tid & 63;
    const int q0 = e0 + (len * wave) / 4;
    const int q1 = e0 + (len * (wave + 1)) / 4;
    __shared__ int wcnt[4][NB];
    __shared__ int wbase[4][NB];

    // phase 1: per-wave bucket counts via ballot (no atomics)
    int c0 = 0, c1 = 0, c2 = 0, c3 = 0;
    for (int base = q0; base < q1; base += 64) {
        int e = base + lane;
        int b = -1;
        if (e < q1) b = src[e] / SRC_PER_B;
        c0 += __popcll(__ballot(b == 0));
        c1 += __popcll(__ballot(b == 1));
        c2 += __popcll(__ballot(b == 2));
        c3 += __popcll(__ballot(b == 3));
    }
    if (lane == 0) { wcnt[wave][0] = c0; wcnt[wave][1] = c1; wcnt[wave][2] = c2; wcnt[wave][3] = c3; }
    __syncthreads();
    if (tid == 0) {
        int acc = e0;
        #pragma unroll
        for (int b = 0; b < NB; ++b) {
            bstart[n * (NB + 1) + b] = acc;
            #pragma unroll
            for (int w = 0; w < 4; ++w) { wbase[w][b] = acc; acc += wcnt[w][b]; }
        }
        bstart[n * (NB + 1) + NB] = acc;   // == e1
    }
    __syncthreads();

    // phase 2: stable scatter, no barriers (cursors are wave-uniform regs)
    int u0 = wbase[wave][0], u1 = wbase[wave][1], u2 = wbase[wave][2], u3 = wbase[wave][3];
    for (int base = q0; base < q1; base += 64) {
        int e = base + lane;
        int s = 0, b = -1;
        if (e < q1) { s = src[e]; b = s / SRC_PER_B; }
        unsigned long long m0 = __ballot(b == 0);
        unsigned long long m1 = __ballot(b == 1);
        unsigned long long m2 = __ballot(b == 2);
        unsigned long long m3 = __ballot(b == 3);
        unsigned long long lt = (1ull << lane) - 1ull;
        if (b == 0)      esrc[u0 + __popcll(m0 & lt)] = s;
        else if (b == 1) esrc[u1 + __popcll(m1 & lt)] = s;
        else if (b == 2) esrc[u2 + __popcll(m2 & lt)] = s;
        else if (b == 3) esrc[u3 + __popcll(m3 & lt)] = s;
        u0 += __popcll(m0); u1 += __popcll(m1); u2 += __popcll(m2); u3 += __popcll(m3);
    }
}

// Layer-0 gather over bucket-partitioned edges. Block (n, b) reads its
// contiguous bucket range; table slice b (3.2 MB) stays L2-resident on
// XCDs {b, b+4} (blockIdx & 3 == b). 128 threads = 2 waves, 4x unroll,
// LDS tree reduce. The LAST block to finish also reduces the NB partials
// into the fp16 P0h table (threadfence + atomic counter; deterministic).
__global__ __launch_bounds__(128) void k_gather0s(const h8* __restrict__ table,
                                                  const int* __restrict__ esrc,
                                                  const int* __restrict__ bstart,
                                                  float* __restrict__ part,
                                                  _Float16* __restrict__ p0h,
                                                  int* __restrict__ gcnt) {
    const int b = blockIdx.x & (NB - 1);
    const int n = blockIdx.x >> 2;
    const int q0 = bstart[n * (NB + 1) + b];
    const int q1 = bstart[n * (NB + 1) + b + 1];
    const int tid = threadIdx.x;
    const int b4 = tid & 3;      // which 16B chunk of the 64B row
    const int g  = tid >> 2;     // 32 edge groups
    float acc[8] = {0.f, 0.f, 0.f, 0.f, 0.f, 0.f, 0.f, 0.f};
    int e = q0 + g;
    for (; e + 96 < q1; e += 128) {
        int s0 = __builtin_nontemporal_load(esrc + e);
        int s1 = __builtin_nontemporal_load(esrc + e + 32);
        int s2 = __builtin_nontemporal_load(esrc + e + 64);
        int s3 = __builtin_nontemporal_load(esrc + e + 96);
        h8 v0 = table[s0 * 4 + b4];
        h8 v1 = table[s1 * 4 + b4];
        h8 v2 = table[s2 * 4 + b4];
        h8 v3 = table[s3 * 4 + b4];
        #pragma unroll
        for (int i = 0; i < 8; ++i)
            acc[i] += (float)v0[i] + (float)v1[i] + (float)v2[i] + (float)v3[i];
    }
    for (; e < q1; e += 32) {
        int s = __builtin_nontemporal_load(esrc + e);
        h8 v = table[s * 4 + b4];
        #pragma unroll
        for (int i = 0; i < 8; ++i) acc[i] += (float)v[i];
    }
    __shared__ float red[32][33];
    #pragma unroll
    for (int i = 0; i < 8; ++i) red[g][b4 * 8 + i] = acc[i];
    __syncthreads();
    #pragma unroll
    for (int s = 16; s >= 1; s >>= 1) {
        if (g < s) {
            #pragma unroll
            for (int i = 0; i < 8; ++i)
                red[g][b4 * 8 + i] += red[g + s][b4 * 8 + i];
        }
        __syncthreads();
    }
    if (tid < 32) part[(b * N1 + n) * 32 + tid] = red[0][tid];

    // last-block partial reduction -> fp16 table for gather1
    __shared__ int isLast;
    __threadfence();
    __syncthreads();
    if (tid == 0) {
        int old = atomicAdd(gcnt, 1);
        isLast = (old == G0_BLOCKS - 1) ? 1 : 0;
    }
    __syncthreads();
    if (isLast) {
        __threadfence();
        const float4* p4 = (const float4*)part;   // 4 slices of 8192 float4
        h2* out2 = (h2*)p0h;
        for (int i = tid; i < 8192; i += 128) {
            float4 a = p4[i], c = p4[8192 + i], d = p4[16384 + i], f = p4[24576 + i];
            float sx = a.x + c.x + d.x + f.x;
            float sy = a.y + c.y + d.y + f.y;
            float sz = a.z + c.z + d.z + f.z;
            float sw = a.w + c.w + d.w + f.w;
            h2 lo; lo[0] = (_Float16)sx; lo[1] = (_Float16)sy;
            h2 hi; hi[0] = (_Float16)sz; hi[1] = (_Float16)sw;
            out2[i * 2] = lo; out2[i * 2 + 1] = hi;
        }
        if (tid == 0) *gcnt = 0;   // reset for next graph replay
    }
}

// Layer-1 segmented gather-sum over fp16 rows (table P0h, 64 KB, L2-resident).
// Writes S1h (fp16) + cnt1 (segment lengths).
__global__ __launch_bounds__(256) void k_gather1(const h8* __restrict__ table,
                                                 const int* __restrict__ src,
                                                 const int* __restrict__ dst,
                                                 _Float16* __restrict__ out_h,
                                                 float* __restrict__ cnt_out) {
    const int n = blockIdx.x;
    const int e0 = lower_bound_i(dst, NE1, n);
    const int e1 = lower_bound_i(dst, NE1, n + 1);
    const int tid = threadIdx.x;
    const int b4 = tid & 3;
    const int g  = tid >> 2;
    float acc[8] = {0.f, 0.f, 0.f, 0.f, 0.f, 0.f, 0.f, 0.f};
    int e = e0 + g;
    for (; e + 192 < e1; e += 256) {
        int s0 = src[e];
        int s1 = src[e + 64];
        int s2 = src[e + 128];
        int s3 = src[e + 192];
        h8 v0 = table[s0 * 4 + b4];
        h8 v1 = table[s1 * 4 + b4];
        h8 v2 = table[s2 * 4 + b4];
        h8 v3 = table[s3 * 4 + b4];
        #pragma unroll
        for (int i = 0; i < 8; ++i)
            acc[i] += (float)v0[i] + (float)v1[i] + (float)v2[i] + (float)v3[i];
    }
    for (; e < e1; e += 64) {
        int s = src[e];
        h8 v = table[s * 4 + b4];
        #pragma unroll
        for (int i = 0; i < 8; ++i) acc[i] += (float)v[i];
    }
    __shared__ float red[64][33];
    #pragma unroll
    for (int i = 0; i < 8; ++i) red[g][b4 * 8 + i] = acc[i];
    __syncthreads();
    #pragma unroll
    for (int s = 32; s >= 1; s >>= 1) {
        if (g < s) {
            #pragma unroll
            for (int i = 0; i < 8; ++i)
                red[g][b4 * 8 + i] += red[g + s][b4 * 8 + i];
        }
        __syncthreads();
    }
    if (tid < 32) out_h[n * 32 + tid] = (_Float16)red[0][tid];
    else if (tid == 32) cnt_out[n] = (float)(e1 - e0);
}

// Tail: gather2 (8192 edges, 16 KB table) + weight algebra + final output.
// One 1024-thread block; S2/T2/cnt2 live in LDS.
__global__ __launch_bounds__(1024) void k_tail(
    const h8* __restrict__ tableS1, const int* __restrict__ src2,
    const int* __restrict__ dst2, const float* __restrict__ cnt1,
    const float* __restrict__ V0, const float* __restrict__ g0, const float* __restrict__ b0,
    const float* __restrict__ V1, const float* __restrict__ g1, const float* __restrict__ b1,
    const float* __restrict__ V2, const float* __restrict__ g2, const float* __restrict__ b2,
    const float* __restrict__ Vfc, const float* __restrict__ gfc, const float* __restrict__ bfc,
    float* __restrict__ out) {
    const int tid = threadIdx.x;
    __shared__ float S2_l[32][33];
    __shared__ float T2_l[32], cnt2_l[32];
    __shared__ float w0[32], u[64], v[64], p[128], q[128], r[128], b2_l[128];
    __shared__ float M_l[10][33], Kc_l[10];

    // --- phase A: gather2 into LDS. 32 segments x 32 lanes. ---
    {
        const int n = tid >> 5;          // segment
        const int l32 = tid & 31;
        const int b4 = l32 & 3;          // 16B chunk
        const int g  = l32 >> 2;         // 8 edge groups
        const int e0 = lower_bound_i(dst2, NE2, n);
        const int e1 = lower_bound_i(dst2, NE2, n + 1);
        float acc[8] = {0.f, 0.f, 0.f, 0.f, 0.f, 0.f, 0.f, 0.f};
        float tacc = 0.f;
        for (int e = e0 + g; e < e1; e += 8) {
            int s = src2[e];
            h8 vv = tableS1[s * 4 + b4];
            #pragma unroll
            for (int i = 0; i < 8; ++i) acc[i] += (float)vv[i];
            if (b4 == 0) tacc += cnt1[s];
        }
        // butterfly across the 8 edge-groups (lane bits 2..4)
        #pragma unroll
        for (int off = 4; off <= 16; off <<= 1) {
            #pragma unroll
            for (int i = 0; i < 8; ++i) acc[i] += __shfl_xor(acc[i], off);
            tacc += __shfl_xor(tacc, off);
        }
        if (g == 0) {
            #pragma unroll
            for (int i = 0; i < 8; ++i) S2_l[n][b4 * 8 + i] = acc[i];
            if (b4 == 0) { T2_l[n] = tacc; cnt2_l[n] = (float)(e1 - e0); }
        }
    }
    __syncthreads();

    // --- phase B: weight chain ---
    if (tid < 32) {
        float val = V0[tid];
        w0[tid] = g0[tid] * val / fabsf(val);
    }
    if (tid >= 896) {  // independent: stage b2 into LDS (last wave)
        int i = tid - 896;
        b2_l[i] = b2[i];
    }
    __syncthreads();
    if (tid < 64) {
        float nn = 0.f;
        #pragma unroll
        for (int c = 0; c < 32; ++c) { float t = V1[tid * 32 + c]; nn += t * t; }
        float inv = g1[tid] * rsqrtf(nn);
        float su = 0.f, sv = 0.f;
        #pragma unroll
        for (int c = 0; c < 32; ++c) {
            float w = V1[tid * 32 + c] * inv;
            su += w * w0[c]; sv += w * b0[c];
        }
        u[tid] = su; v[tid] = sv;
    }
    __syncthreads();
    if (tid < 128) {
        float nn = 0.f;
        #pragma unroll
        for (int c = 0; c < 64; ++c) { float t = V2[tid * 64 + c]; nn += t * t; }
        float inv = g2[tid] * rsqrtf(nn);
        float sp = 0.f, sq = 0.f, sr = 0.f;
        #pragma unroll
        for (int c = 0; c < 64; ++c) {
            float w = V2[tid * 64 + c] * inv;
            sp += w * u[c]; sq += w * v[c]; sr += w * b1[c];
        }
        p[tid] = sp; q[tid] = sq; r[tid] = sr;
    }
    __syncthreads();

    // --- phase C: per-class Vfc pass. class k = tid>>5, lane n3 = tid&31. ---
    {
        const int k = tid >> 5, n3 = tid & 31;
        if (k < NCLS) {
            float nn = 0.f, mk = 0.f, mq = 0.f, mr = 0.f, mb = 0.f;
            #pragma unroll 8
            for (int o = 0; o < 128; ++o) {
                float w = Vfc[k * 4096 + o * 32 + n3];
                nn += w * w;
                mk += w * p[o]; mq += w * q[o]; mr += w * r[o]; mb += w * b2_l[o];
            }
            #pragma unroll
            for (int off = 16; off; off >>= 1) nn += __shfl_xor(nn, off);
            float scale = gfc[k] * rsqrtf(nn);
            M_l[k][n3] = scale * mk;
            float kcp = scale * (mq * T2_l[n3] + mr * cnt2_l[n3] + mb);
            #pragma unroll
            for (int off = 16; off; off >>= 1) kcp += __shfl_xor(kcp, off);
            if (n3 == 0) Kc_l[k] = kcp + bfc[k];
        }
    }
    __syncthreads();

    // --- phase D: out[b,k] = sum_n3 M[k][n3] * S2[n3][b] + Kc[k] ---
    {
        const int k = tid >> 5, b = tid & 31;
        if (k < NCLS) {
            float s = 0.f;
            #pragma unroll
            for (int n = 0; n < 32; ++n) s += M_l[k][n] * S2_l[n][b];
            out[b * NCLS + k] = s + Kc_l[k];
        }
    }
}

extern "C" void kernel_launch(void* const* d_in, const int* in_sizes, int n_in,
                              void* d_out, int out_size, void* d_ws, size_t ws_size,
                              hipStream_t stream) {
    const float* x   = (const float*)d_in[0];
    const int* src0  = (const int*)d_in[1];
    const int* dst0  = (const int*)d_in[2];
    const int* src1  = (const int*)d_in[3];
    const int* dst1  = (const int*)d_in[4];
    const int* src2  = (const int*)d_in[5];
    const int* dst2  = (const int*)d_in[6];
    const float* V0  = (const float*)d_in[7];
    const float* g0  = (const float*)d_in[8];
    const float* b0  = (const float*)d_in[9];
    const float* V1  = (const float*)d_in[10];
    const float* g1  = (const float*)d_in[11];
    const float* b1  = (const float*)d_in[12];
    const float* V2  = (const float*)d_in[13];
    const float* g2  = (const float*)d_in[14];
    const float* b2  = (const float*)d_in[15];
    const float* Vfc = (const float*)d_in[16];
    const float* gfc = (const float*)d_in[17];
    const float* bfc = (const float*)d_in[18];

    char* ws = (char*)d_ws;
    _Float16* xt  = (_Float16*)(ws);                 // 12,800,000 B
    int* esrc     = (int*)(ws + 12800000);           // 8,192,000 B
    int* bstart   = (int*)(ws + 20992000);           // 20,480 B
    float* P0p    = (float*)(ws + 21012480);         // 524,288 B
    _Float16* P0h = (_Float16*)(ws + 21536768);      // 65,536 B
    _Float16* S1h = (_Float16*)(ws + 21602304);      // 16,384 B
    float* cnt1   = (float*)(ws + 21618688);         // 1,024 B
    int* gcnt     = (int*)(ws + 21619712);           // 4 B

    k_transpose<<<(N0 + 63) / 64, 256, 0, stream>>>(x, (h2*)xt);
    k_partition<<<N1, 256, 0, stream>>>(src0, dst0, esrc, bstart, gcnt);
    k_gather0s<<<G0_BLOCKS, 128, 0, stream>>>((const h8*)xt, esrc, bstart,
                                              P0p, P0h, gcnt);
    k_gather1<<<N2, 256, 0, stream>>>((const h8*)P0h, src1, dst1, S1h, cnt1);
    k_tail<<<1, 1024, 0, stream>>>((const h8*)S1h, src2, dst2, cnt1,
                                   V0, g0, b0, V1, g1, b1, V2, g2, b2,
                                   Vfc, gfc, bfc, (float*)d_out);
}

// Round 10
// 98.288 us; speedup vs baseline: 2.7850x; 2.7850x over previous
//
#include <hip/hip_runtime.h>
#include <math.h>

#define N0 200000
#define N1 1024
#define N2 256
#define N3 32
#define NE0 2048000
#define NE1 262144
#define NE2 8192
#define BATCH 32
#define NCLS 10
#define NB 4            // src-range buckets for gather0 (XCD L2 partitioning)
#define SRC_PER_B 50000 // N0 / NB

typedef _Float16 h2 __attribute__((ext_vector_type(2)));
typedef _Float16 h8 __attribute__((ext_vector_type(8)));

__device__ __forceinline__ int lower_bound_i(const int* __restrict__ a, int n, int key) {
    int lo = 0, hi = n;
    while (lo < hi) {
        int mid = (lo + hi) >> 1;
        if (a[mid] < key) lo = mid + 1; else hi = mid;
    }
    return lo;
}

// x (32, 200000) fp32 -> xt (200000, 32) fp16 rows (64 B each), LDS tiled.
__global__ __launch_bounds__(256) void k_transpose(const float* __restrict__ x,
                                                   h2* __restrict__ xt) {
    __shared__ float tile[32][65];
    const int col0 = blockIdx.x * 64;
    const int tid = threadIdx.x;
    const int c = tid & 63, r0 = tid >> 6;       // 4 row-lanes
    #pragma unroll
    for (int r = r0; r < 32; r += 4) {
        int col = col0 + c;
        tile[r][c] = (col < N0) ? x[r * N0 + col] : 0.f;
    }
    __syncthreads();
    const int bb = (tid & 15) * 2, c0 = tid >> 4; // 16 col-lanes, 2 batch rows/thread
    #pragma unroll
    for (int cc = c0; cc < 64; cc += 16) {
        int col = col0 + cc;
        if (col < N0) {
            h2 v;
            v[0] = (_Float16)tile[bb][cc];
            v[1] = (_Float16)tile[bb + 1][cc];
            xt[col * 16 + (bb >> 1)] = v;
        }
    }
}

// Stable 4-way partition of each dst-segment's src list by src bucket.
// Inline binary search for segment bounds (latency overlapped across 1024
// blocks). Ballot-popcount counting (no atomics), ballot-rank stable scatter.
// NO cross-workgroup signaling (round-9 lesson: device-scope fences in a
// wide kernel serialize L2 writebacks -> 191 us disaster).
__global__ __launch_bounds__(256) void k_partition(const int* __restrict__ src,
                                                   const int* __restrict__ dst,
                                                   int* __restrict__ esrc,
                                                   int* __restrict__ bstart) {
    const int n = blockIdx.x;
    const int tid = threadIdx.x;
    const int e0 = lower_bound_i(dst, NE0, n);
    const int e1 = lower_bound_i(dst, NE0, n + 1);
    const int len = e1 - e0;
    const int wave = tid >> 6, lane = tid & 63;
    const int q0 = e0 + (len * wave) / 4;
    const int q1 = e0 + (len * (wave + 1)) / 4;
    __shared__ int wcnt[4][NB];
    __shared__ int wbase[4][NB];

    // phase 1: per-wave bucket counts via ballot (no atomics)
    int c0 = 0, c1 = 0, c2 = 0, c3 = 0;
    for (int base = q0; base < q1; base += 64) {
        int e = base + lane;
        int b = -1;
        if (e < q1) b = src[e] / SRC_PER_B;
        c0 += __popcll(__ballot(b == 0));
        c1 += __popcll(__ballot(b == 1));
        c2 += __popcll(__ballot(b == 2));
        c3 += __popcll(__ballot(b == 3));
    }
    if (lane == 0) { wcnt[wave][0] = c0; wcnt[wave][1] = c1; wcnt[wave][2] = c2; wcnt[wave][3] = c3; }
    __syncthreads();
    if (tid == 0) {
        int acc = e0;
        #pragma unroll
        for (int b = 0; b < NB; ++b) {
            bstart[n * (NB + 1) + b] = acc;
            #pragma unroll
            for (int w = 0; w < 4; ++w) { wbase[w][b] = acc; acc += wcnt[w][b]; }
        }
        bstart[n * (NB + 1) + NB] = acc;   // == e1
    }
    __syncthreads();

    // phase 2: stable scatter, no barriers (cursors are wave-uniform regs)
    int u0 = wbase[wave][0], u1 = wbase[wave][1], u2 = wbase[wave][2], u3 = wbase[wave][3];
    for (int base = q0; base < q1; base += 64) {
        int e = base + lane;
        int s = 0, b = -1;
        if (e < q1) { s = src[e]; b = s / SRC_PER_B; }
        unsigned long long m0 = __ballot(b == 0);
        unsigned long long m1 = __ballot(b == 1);
        unsigned long long m2 = __ballot(b == 2);
        unsigned long long m3 = __ballot(b == 3);
        unsigned long long lt = (1ull << lane) - 1ull;
        if (b == 0)      esrc[u0 + __popcll(m0 & lt)] = s;
        else if (b == 1) esrc[u1 + __popcll(m1 & lt)] = s;
        else if (b == 2) esrc[u2 + __popcll(m2 & lt)] = s;
        else if (b == 3) esrc[u3 + __popcll(m3 & lt)] = s;
        u0 += __popcll(m0); u1 += __popcll(m1); u2 += __popcll(m2); u3 += __popcll(m3);
    }
}

// Layer-0 gather over bucket-partitioned edges. Block (n, b) reads its
// contiguous bucket range; table slice b (3.2 MB) stays L2-resident on
// XCDs {b, b+4} (blockIdx & 3 == b). 128 threads = 2 waves, 4x unroll,
// LDS tree reduce. No cross-block signaling.
__global__ __launch_bounds__(128) void k_gather0s(const h8* __restrict__ table,
                                                  const int* __restrict__ esrc,
                                                  const int* __restrict__ bstart,
                                                  float* __restrict__ part) {
    const int b = blockIdx.x & (NB - 1);
    const int n = blockIdx.x >> 2;
    const int q0 = bstart[n * (NB + 1) + b];
    const int q1 = bstart[n * (NB + 1) + b + 1];
    const int tid = threadIdx.x;
    const int b4 = tid & 3;      // which 16B chunk of the 64B row
    const int g  = tid >> 2;     // 32 edge groups
    float acc[8] = {0.f, 0.f, 0.f, 0.f, 0.f, 0.f, 0.f, 0.f};
    int e = q0 + g;
    for (; e + 96 < q1; e += 128) {
        int s0 = __builtin_nontemporal_load(esrc + e);
        int s1 = __builtin_nontemporal_load(esrc + e + 32);
        int s2 = __builtin_nontemporal_load(esrc + e + 64);
        int s3 = __builtin_nontemporal_load(esrc + e + 96);
        h8 v0 = table[s0 * 4 + b4];
        h8 v1 = table[s1 * 4 + b4];
        h8 v2 = table[s2 * 4 + b4];
        h8 v3 = table[s3 * 4 + b4];
        #pragma unroll
        for (int i = 0; i < 8; ++i)
            acc[i] += (float)v0[i] + (float)v1[i] + (float)v2[i] + (float)v3[i];
    }
    for (; e < q1; e += 32) {
        int s = __builtin_nontemporal_load(esrc + e);
        h8 v = table[s * 4 + b4];
        #pragma unroll
        for (int i = 0; i < 8; ++i) acc[i] += (float)v[i];
    }
    __shared__ float red[32][33];
    #pragma unroll
    for (int i = 0; i < 8; ++i) red[g][b4 * 8 + i] = acc[i];
    __syncthreads();
    #pragma unroll
    for (int s = 16; s >= 1; s >>= 1) {
        if (g < s) {
            #pragma unroll
            for (int i = 0; i < 8; ++i)
                red[g][b4 * 8 + i] += red[g + s][b4 * 8 + i];
        }
        __syncthreads();
    }
    if (tid < 32) part[(b * N1 + n) * 32 + tid] = red[0][tid];
}

// Combine NB bucket partials -> fp16 table for gather1.
__global__ __launch_bounds__(256) void k_reduceP(const float* __restrict__ part,
                                                 _Float16* __restrict__ out) {
    int i = blockIdx.x * 256 + threadIdx.x;   // [0, N1*32)
    float s = part[i] + part[N1 * 32 + i] + part[2 * N1 * 32 + i] + part[3 * N1 * 32 + i];
    out[i] = (_Float16)s;
}

// Layer-1 segmented gather-sum over fp16 rows (table P0h, 64 KB, L2-resident).
__global__ __launch_bounds__(256) void k_gather1(const h8* __restrict__ table,
                                                 const int* __restrict__ src,
                                                 const int* __restrict__ dst,
                                                 _Float16* __restrict__ out_h,
                                                 float* __restrict__ cnt_out) {
    const int n = blockIdx.x;
    const int e0 = lower_bound_i(dst, NE1, n);
    const int e1 = lower_bound_i(dst, NE1, n + 1);
    const int tid = threadIdx.x;
    const int b4 = tid & 3;
    const int g  = tid >> 2;
    float acc[8] = {0.f, 0.f, 0.f, 0.f, 0.f, 0.f, 0.f, 0.f};
    int e = e0 + g;
    for (; e + 192 < e1; e += 256) {
        int s0 = src[e];
        int s1 = src[e + 64];
        int s2 = src[e + 128];
        int s3 = src[e + 192];
        h8 v0 = table[s0 * 4 + b4];
        h8 v1 = table[s1 * 4 + b4];
        h8 v2 = table[s2 * 4 + b4];
        h8 v3 = table[s3 * 4 + b4];
        #pragma unroll
        for (int i = 0; i < 8; ++i)
            acc[i] += (float)v0[i] + (float)v1[i] + (float)v2[i] + (float)v3[i];
    }
    for (; e < e1; e += 64) {
        int s = src[e];
        h8 v = table[s * 4 + b4];
        #pragma unroll
        for (int i = 0; i < 8; ++i) acc[i] += (float)v[i];
    }
    __shared__ float red[64][33];
    #pragma unroll
    for (int i = 0; i < 8; ++i) red[g][b4 * 8 + i] = acc[i];
    __syncthreads();
    #pragma unroll
    for (int s = 32; s >= 1; s >>= 1) {
        if (g < s) {
            #pragma unroll
            for (int i = 0; i < 8; ++i)
                red[g][b4 * 8 + i] += red[g + s][b4 * 8 + i];
        }
        __syncthreads();
    }
    if (tid < 32) out_h[n * 32 + tid] = (_Float16)red[0][tid];
    else if (tid == 32) cnt_out[n] = (float)(e1 - e0);
}

// Tail: gather2 (8192 edges, 16 KB table) + weight algebra + final output.
// One 1024-thread block; S2/T2/cnt2 live in LDS.
__global__ __launch_bounds__(1024) void k_tail(
    const h8* __restrict__ tableS1, const int* __restrict__ src2,
    const int* __restrict__ dst2, const float* __restrict__ cnt1,
    const float* __restrict__ V0, const float* __restrict__ g0, const float* __restrict__ b0,
    const float* __restrict__ V1, const float* __restrict__ g1, const float* __restrict__ b1,
    const float* __restrict__ V2, const float* __restrict__ g2, const float* __restrict__ b2,
    const float* __restrict__ Vfc, const float* __restrict__ gfc, const float* __restrict__ bfc,
    float* __restrict__ out) {
    const int tid = threadIdx.x;
    __shared__ float S2_l[32][33];
    __shared__ float T2_l[32], cnt2_l[32];
    __shared__ float w0[32], u[64], v[64], p[128], q[128], r[128], b2_l[128];
    __shared__ float M_l[10][33], Kc_l[10];

    // --- phase A: gather2 into LDS. 32 segments x 32 lanes. ---
    {
        const int n = tid >> 5;          // segment
        const int l32 = tid & 31;
        const int b4 = l32 & 3;          // 16B chunk
        const int g  = l32 >> 2;         // 8 edge groups
        const int e0 = lower_bound_i(dst2, NE2, n);
        const int e1 = lower_bound_i(dst2, NE2, n + 1);
        float acc[8] = {0.f, 0.f, 0.f, 0.f, 0.f, 0.f, 0.f, 0.f};
        float tacc = 0.f;
        for (int e = e0 + g; e < e1; e += 8) {
            int s = src2[e];
            h8 vv = tableS1[s * 4 + b4];
            #pragma unroll
            for (int i = 0; i < 8; ++i) acc[i] += (float)vv[i];
            if (b4 == 0) tacc += cnt1[s];
        }
        // butterfly across the 8 edge-groups (lane bits 2..4)
        #pragma unroll
        for (int off = 4; off <= 16; off <<= 1) {
            #pragma unroll
            for (int i = 0; i < 8; ++i) acc[i] += __shfl_xor(acc[i], off);
            tacc += __shfl_xor(tacc, off);
        }
        if (g == 0) {
            #pragma unroll
            for (int i = 0; i < 8; ++i) S2_l[n][b4 * 8 + i] = acc[i];
            if (b4 == 0) { T2_l[n] = tacc; cnt2_l[n] = (float)(e1 - e0); }
        }
    }
    __syncthreads();

    // --- phase B: weight chain ---
    if (tid < 32) {
        float val = V0[tid];
        w0[tid] = g0[tid] * val / fabsf(val);
    }
    if (tid >= 896) {  // independent: stage b2 into LDS (last wave)
        int i = tid - 896;
        b2_l[i] = b2[i];
    }
    __syncthreads();
    if (tid < 64) {
        float nn = 0.f;
        #pragma unroll
        for (int c = 0; c < 32; ++c) { float t = V1[tid * 32 + c]; nn += t * t; }
        float inv = g1[tid] * rsqrtf(nn);
        float su = 0.f, sv = 0.f;
        #pragma unroll
        for (int c = 0; c < 32; ++c) {
            float w = V1[tid * 32 + c] * inv;
            su += w * w0[c]; sv += w * b0[c];
        }
        u[tid] = su; v[tid] = sv;
    }
    __syncthreads();
    if (tid < 128) {
        float nn = 0.f;
        #pragma unroll
        for (int c = 0; c < 64; ++c) { float t = V2[tid * 64 + c]; nn += t * t; }
        float inv = g2[tid] * rsqrtf(nn);
        float sp = 0.f, sq = 0.f, sr = 0.f;
        #pragma unroll
        for (int c = 0; c < 64; ++c) {
            float w = V2[tid * 64 + c] * inv;
            sp += w * u[c]; sq += w * v[c]; sr += w * b1[c];
        }
        p[tid] = sp; q[tid] = sq; r[tid] = sr;
    }
    __syncthreads();

    // --- phase C: per-class Vfc pass. class k = tid>>5, lane n3 = tid&31. ---
    {
        const int k = tid >> 5, n3 = tid & 31;
        if (k < NCLS) {
            float nn = 0.f, mk = 0.f, mq = 0.f, mr = 0.f, mb = 0.f;
            #pragma unroll 8
            for (int o = 0; o < 128; ++o) {
                float w = Vfc[k * 4096 + o * 32 + n3];
                nn += w * w;
                mk += w * p[o]; mq += w * q[o]; mr += w * r[o]; mb += w * b2_l[o];
            }
            #pragma unroll
            for (int off = 16; off; off >>= 1) nn += __shfl_xor(nn, off);
            float scale = gfc[k] * rsqrtf(nn);
            M_l[k][n3] = scale * mk;
            float kcp = scale * (mq * T2_l[n3] + mr * cnt2_l[n3] + mb);
            #pragma unroll
            for (int off = 16; off; off >>= 1) kcp += __shfl_xor(kcp, off);
            if (n3 == 0) Kc_l[k] = kcp + bfc[k];
        }
    }
    __syncthreads();

    // --- phase D: out[b,k] = sum_n3 M[k][n3] * S2[n3][b] + Kc[k] ---
    {
        const int k = tid >> 5, b = tid & 31;
        if (k < NCLS) {
            float s = 0.f;
            #pragma unroll
            for (int n = 0; n < 32; ++n) s += M_l[k][n] * S2_l[n][b];
            out[b * NCLS + k] = s + Kc_l[k];
        }
    }
}

extern "C" void kernel_launch(void* const* d_in, const int* in_sizes, int n_in,
                              void* d_out, int out_size, void* d_ws, size_t ws_size,
                              hipStream_t stream) {
    const float* x   = (const float*)d_in[0];
    const int* src0  = (const int*)d_in[1];
    const int* dst0  = (const int*)d_in[2];
    const int* src1  = (const int*)d_in[3];
    const int* dst1  = (const int*)d_in[4];
    const int* src2  = (const int*)d_in[5];
    const int* dst2  = (const int*)d_in[6];
    const float* V0  = (const float*)d_in[7];
    const float* g0  = (const float*)d_in[8];
    const float* b0  = (const float*)d_in[9];
    const float* V1  = (const float*)d_in[10];
    const float* g1  = (const float*)d_in[11];
    const float* b1  = (const float*)d_in[12];
    const float* V2  = (const float*)d_in[13];
    const float* g2  = (const float*)d_in[14];
    const float* b2  = (const float*)d_in[15];
    const float* Vfc = (const float*)d_in[16];
    const float* gfc = (const float*)d_in[17];
    const float* bfc = (const float*)d_in[18];

    char* ws = (char*)d_ws;
    _Float16* xt  = (_Float16*)(ws);                 // 12,800,000 B
    int* esrc     = (int*)(ws + 12800000);           // 8,192,000 B
    int* bstart   = (int*)(ws + 20992000);           // 20,480 B
    float* P0p    = (float*)(ws + 21012480);         // 524,288 B
    _Float16* P0h = (_Float16*)(ws + 21536768);      // 65,536 B
    _Float16* S1h = (_Float16*)(ws + 21602304);      // 16,384 B
    float* cnt1   = (float*)(ws + 21618688);         // 1,024 B

    k_transpose<<<(N0 + 63) / 64, 256, 0, stream>>>(x, (h2*)xt);
    k_partition<<<N1, 256, 0, stream>>>(src0, dst0, esrc, bstart);
    k_gather0s<<<N1 * NB, 128, 0, stream>>>((const h8*)xt, esrc, bstart, P0p);
    k_reduceP<<<(N1 * 32) / 256, 256, 0, stream>>>(P0p, P0h);
    k_gather1<<<N2, 256, 0, stream>>>((const h8*)P0h, src1, dst1, S1h, cnt1);
    k_tail<<<1, 1024, 0, stream>>>((const h8*)S1h, src2, dst2, cnt1,
                                   V0, g0, b0, V1, g1, b1, V2, g2, b2,
                                   Vfc, gfc, bfc, (float*)d_out);
}

// Round 11
// 81.413 us; speedup vs baseline: 3.3622x; 1.2073x over previous
//
#include <hip/hip_runtime.h>
#include <math.h>

#define N0 200000
#define N1 1024
#define N2 256
#define N3 32
#define NE0 2048000
#define NE1 262144
#define NE2 8192
#define BATCH 32
#define NCLS 10
#define NB 4            // src-range buckets for gather0 (XCD L2 partitioning)
#define SRC_PER_B 50000 // N0 / NB

typedef _Float16 h2 __attribute__((ext_vector_type(2)));
typedef _Float16 h8 __attribute__((ext_vector_type(8)));

__device__ __forceinline__ int lower_bound_i(const int* __restrict__ a, int n, int key) {
    int lo = 0, hi = n;
    while (lo < hi) {
        int mid = (lo + hi) >> 1;
        if (a[mid] < key) lo = mid + 1; else hi = mid;
    }
    return lo;
}

// x (32, 200000) fp32 -> xt (200000, 32) fp16 rows (64 B each), LDS tiled.
__global__ __launch_bounds__(256) void k_transpose(const float* __restrict__ x,
                                                   h2* __restrict__ xt) {
    __shared__ float tile[32][65];
    const int col0 = blockIdx.x * 64;
    const int tid = threadIdx.x;
    const int c = tid & 63, r0 = tid >> 6;       // 4 row-lanes
    #pragma unroll
    for (int r = r0; r < 32; r += 4) {
        int col = col0 + c;
        tile[r][c] = (col < N0) ? x[r * N0 + col] : 0.f;
    }
    __syncthreads();
    const int bb = (tid & 15) * 2, c0 = tid >> 4; // 16 col-lanes, 2 batch rows/thread
    #pragma unroll
    for (int cc = c0; cc < 64; cc += 16) {
        int col = col0 + cc;
        if (col < N0) {
            h2 v;
            v[0] = (_Float16)tile[bb][cc];
            v[1] = (_Float16)tile[bb + 1][cc];
            xt[col * 16 + (bb >> 1)] = v;
        }
    }
}

// Stable 4-way partition of each dst-segment's src list by src bucket.
// Inline binary search for bounds (latency overlapped across 1024 blocks).
// Ballot-popcount counting (no atomics), ballot-rank stable scatter.
// NO cross-workgroup signaling (round-9 lesson: device fences in a wide
// kernel -> L2 writeback serialization disaster).
__global__ __launch_bounds__(256) void k_partition(const int* __restrict__ src,
                                                   const int* __restrict__ dst,
                                                   int* __restrict__ esrc,
                                                   int* __restrict__ bstart) {
    const int n = blockIdx.x;
    const int tid = threadIdx.x;
    const int e0 = lower_bound_i(dst, NE0, n);
    const int e1 = lower_bound_i(dst, NE0, n + 1);
    const int len = e1 - e0;
    const int wave = tid >> 6, lane = tid & 63;
    const int q0 = e0 + (len * wave) / 4;
    const int q1 = e0 + (len * (wave + 1)) / 4;
    __shared__ int wcnt[4][NB];
    __shared__ int wbase[4][NB];

    // phase 1: per-wave bucket counts via ballot (no atomics)
    int c0 = 0, c1 = 0, c2 = 0, c3 = 0;
    for (int base = q0; base < q1; base += 64) {
        int e = base + lane;
        int b = -1;
        if (e < q1) b = src[e] / SRC_PER_B;
        c0 += __popcll(__ballot(b == 0));
        c1 += __popcll(__ballot(b == 1));
        c2 += __popcll(__ballot(b == 2));
        c3 += __popcll(__ballot(b == 3));
    }
    if (lane == 0) { wcnt[wave][0] = c0; wcnt[wave][1] = c1; wcnt[wave][2] = c2; wcnt[wave][3] = c3; }
    __syncthreads();
    if (tid == 0) {
        int acc = e0;
        #pragma unroll
        for (int b = 0; b < NB; ++b) {
            bstart[n * (NB + 1) + b] = acc;
            #pragma unroll
            for (int w = 0; w < 4; ++w) { wbase[w][b] = acc; acc += wcnt[w][b]; }
        }
        bstart[n * (NB + 1) + NB] = acc;   // == e1
    }
    __syncthreads();

    // phase 2: stable scatter, no barriers (cursors are wave-uniform regs)
    int u0 = wbase[wave][0], u1 = wbase[wave][1], u2 = wbase[wave][2], u3 = wbase[wave][3];
    for (int base = q0; base < q1; base += 64) {
        int e = base + lane;
        int s = 0, b = -1;
        if (e < q1) { s = src[e]; b = s / SRC_PER_B; }
        unsigned long long m0 = __ballot(b == 0);
        unsigned long long m1 = __ballot(b == 1);
        unsigned long long m2 = __ballot(b == 2);
        unsigned long long m3 = __ballot(b == 3);
        unsigned long long lt = (1ull << lane) - 1ull;
        if (b == 0)      esrc[u0 + __popcll(m0 & lt)] = s;
        else if (b == 1) esrc[u1 + __popcll(m1 & lt)] = s;
        else if (b == 2) esrc[u2 + __popcll(m2 & lt)] = s;
        else if (b == 3) esrc[u3 + __popcll(m3 & lt)] = s;
        u0 += __popcll(m0); u1 += __popcll(m1); u2 += __popcll(m2); u3 += __popcll(m3);
    }
}

// Layer-0 gather over bucket-partitioned edges. Block (n, b) reads its
// contiguous bucket range; table slice b (3.2 MB) stays L2-resident on
// XCDs {b, b+4} (blockIdx & 3 == b). 128 threads = 2 waves, 4x unroll,
// LDS tree reduce. No cross-block signaling.
__global__ __launch_bounds__(128) void k_gather0s(const h8* __restrict__ table,
                                                  const int* __restrict__ esrc,
                                                  const int* __restrict__ bstart,
                                                  float* __restrict__ part) {
    const int b = blockIdx.x & (NB - 1);
    const int n = blockIdx.x >> 2;
    const int q0 = bstart[n * (NB + 1) + b];
    const int q1 = bstart[n * (NB + 1) + b + 1];
    const int tid = threadIdx.x;
    const int b4 = tid & 3;      // which 16B chunk of the 64B row
    const int g  = tid >> 2;     // 32 edge groups
    float acc[8] = {0.f, 0.f, 0.f, 0.f, 0.f, 0.f, 0.f, 0.f};
    int e = q0 + g;
    for (; e + 96 < q1; e += 128) {
        int s0 = __builtin_nontemporal_load(esrc + e);
        int s1 = __builtin_nontemporal_load(esrc + e + 32);
        int s2 = __builtin_nontemporal_load(esrc + e + 64);
        int s3 = __builtin_nontemporal_load(esrc + e + 96);
        h8 v0 = table[s0 * 4 + b4];
        h8 v1 = table[s1 * 4 + b4];
        h8 v2 = table[s2 * 4 + b4];
        h8 v3 = table[s3 * 4 + b4];
        #pragma unroll
        for (int i = 0; i < 8; ++i)
            acc[i] += (float)v0[i] + (float)v1[i] + (float)v2[i] + (float)v3[i];
    }
    for (; e < q1; e += 32) {
        int s = __builtin_nontemporal_load(esrc + e);
        h8 v = table[s * 4 + b4];
        #pragma unroll
        for (int i = 0; i < 8; ++i) acc[i] += (float)v[i];
    }
    __shared__ float red[32][33];
    #pragma unroll
    for (int i = 0; i < 8; ++i) red[g][b4 * 8 + i] = acc[i];
    __syncthreads();
    #pragma unroll
    for (int s = 16; s >= 1; s >>= 1) {
        if (g < s) {
            #pragma unroll
            for (int i = 0; i < 8; ++i)
                red[g][b4 * 8 + i] += red[g + s][b4 * 8 + i];
        }
        __syncthreads();
    }
    if (tid < 32) part[(b * N1 + n) * 32 + tid] = red[0][tid];
}

// Combine NB bucket partials -> fp16 table for gather1.
__global__ __launch_bounds__(256) void k_reduceP(const float* __restrict__ part,
                                                 _Float16* __restrict__ out) {
    int i = blockIdx.x * 256 + threadIdx.x;   // [0, N1*32)
    float s = part[i] + part[N1 * 32 + i] + part[2 * N1 * 32 + i] + part[3 * N1 * 32 + i];
    out[i] = (_Float16)s;
}

// Layer-1 segmented gather-sum over fp16 rows (table P0h, 64 KB, L2-resident).
__global__ __launch_bounds__(256) void k_gather1(const h8* __restrict__ table,
                                                 const int* __restrict__ src,
                                                 const int* __restrict__ dst,
                                                 _Float16* __restrict__ out_h,
                                                 float* __restrict__ cnt_out) {
    const int n = blockIdx.x;
    const int e0 = lower_bound_i(dst, NE1, n);
    const int e1 = lower_bound_i(dst, NE1, n + 1);
    const int tid = threadIdx.x;
    const int b4 = tid & 3;
    const int g  = tid >> 2;
    float acc[8] = {0.f, 0.f, 0.f, 0.f, 0.f, 0.f, 0.f, 0.f};
    int e = e0 + g;
    for (; e + 192 < e1; e += 256) {
        int s0 = src[e];
        int s1 = src[e + 64];
        int s2 = src[e + 128];
        int s3 = src[e + 192];
        h8 v0 = table[s0 * 4 + b4];
        h8 v1 = table[s1 * 4 + b4];
        h8 v2 = table[s2 * 4 + b4];
        h8 v3 = table[s3 * 4 + b4];
        #pragma unroll
        for (int i = 0; i < 8; ++i)
            acc[i] += (float)v0[i] + (float)v1[i] + (float)v2[i] + (float)v3[i];
    }
    for (; e < e1; e += 64) {
        int s = src[e];
        h8 v = table[s * 4 + b4];
        #pragma unroll
        for (int i = 0; i < 8; ++i) acc[i] += (float)v[i];
    }
    __shared__ float red[64][33];
    #pragma unroll
    for (int i = 0; i < 8; ++i) red[g][b4 * 8 + i] = acc[i];
    __syncthreads();
    #pragma unroll
    for (int s = 32; s >= 1; s >>= 1) {
        if (g < s) {
            #pragma unroll
            for (int i = 0; i < 8; ++i)
                red[g][b4 * 8 + i] += red[g + s][b4 * 8 + i];
        }
        __syncthreads();
    }
    if (tid < 32) out_h[n * 32 + tid] = (_Float16)red[0][tid];
    else if (tid == 32) cnt_out[n] = (float)(e1 - e0);
}

// Layer-2 gather (32 segments, 16 KB table): writes fp32 S2, T2, cnt2.
__global__ __launch_bounds__(256) void k_gather2(const h8* __restrict__ table,
                                                 const int* __restrict__ src,
                                                 const int* __restrict__ dst,
                                                 const float* __restrict__ cnt_in,
                                                 float* __restrict__ out_f,
                                                 float* __restrict__ cnt_out,
                                                 float* __restrict__ t_out) {
    const int n = blockIdx.x;
    const int e0 = lower_bound_i(dst, NE2, n);
    const int e1 = lower_bound_i(dst, NE2, n + 1);
    const int tid = threadIdx.x;
    const int b4 = tid & 3;
    const int g  = tid >> 2;
    float acc[8] = {0.f, 0.f, 0.f, 0.f, 0.f, 0.f, 0.f, 0.f};
    float tacc = 0.f;
    for (int e = e0 + g; e < e1; e += 64) {
        int s = src[e];
        h8 v = table[s * 4 + b4];
        #pragma unroll
        for (int i = 0; i < 8; ++i) acc[i] += (float)v[i];
        if (b4 == 0) tacc += cnt_in[s];
    }
    __shared__ float red[64][33];
    __shared__ float tred[64];
    #pragma unroll
    for (int i = 0; i < 8; ++i) red[g][b4 * 8 + i] = acc[i];
    if (b4 == 0) tred[g] = tacc;
    __syncthreads();
    #pragma unroll
    for (int s = 32; s >= 1; s >>= 1) {
        if (g < s) {
            #pragma unroll
            for (int i = 0; i < 8; ++i)
                red[g][b4 * 8 + i] += red[g + s][b4 * 8 + i];
            if (b4 == 0) tred[g] += tred[g + s];
        }
        __syncthreads();
    }
    if (tid < 32) out_f[n * 32 + tid] = red[0][tid];
    else if (tid == 32) cnt_out[n] = (float)(e1 - e0);
    else if (tid == 33) t_out[n] = tred[0];
}

// Weight algebra + final output. One block per class k (10 blocks, 256 threads).
// Redundant cheap weight chain per block; one coalesced 16 KB Vfc-row pass.
__global__ __launch_bounds__(256) void k_out(
    const float* __restrict__ V0, const float* __restrict__ g0, const float* __restrict__ b0,
    const float* __restrict__ V1, const float* __restrict__ g1, const float* __restrict__ b1,
    const float* __restrict__ V2, const float* __restrict__ g2, const float* __restrict__ b2,
    const float* __restrict__ Vfc, const float* __restrict__ gfc, const float* __restrict__ bfc,
    const float* __restrict__ S2, const float* __restrict__ T2, const float* __restrict__ cnt2,
    float* __restrict__ out) {
    const int k = blockIdx.x;
    const int tid = threadIdx.x;
    __shared__ float w0[32], u[64], v[64], p[128], q[128], r[128];
    __shared__ float redA[8][32], redB[8][32], redC[8][32], redD[8][32];
    __shared__ float nnred[4];
    __shared__ float M[32];
    __shared__ float scale_s, Kc_s;

    if (tid < 32) {
        float val = V0[tid];
        w0[tid] = g0[tid] * val / fabsf(val);
    }
    __syncthreads();
    if (tid < 64) {
        float nn = 0.f;
        #pragma unroll
        for (int c = 0; c < 32; ++c) { float t = V1[tid * 32 + c]; nn += t * t; }
        float inv = g1[tid] * rsqrtf(nn);
        float su = 0.f, sv = 0.f;
        #pragma unroll
        for (int c = 0; c < 32; ++c) {
            float w = V1[tid * 32 + c] * inv;
            su += w * w0[c]; sv += w * b0[c];
        }
        u[tid] = su; v[tid] = sv;
    }
    __syncthreads();
    if (tid < 128) {
        float nn = 0.f;
        #pragma unroll
        for (int c = 0; c < 64; ++c) { float t = V2[tid * 64 + c]; nn += t * t; }
        float inv = g2[tid] * rsqrtf(nn);
        float sp = 0.f, sq = 0.f, sr = 0.f;
        #pragma unroll
        for (int c = 0; c < 64; ++c) {
            float w = V2[tid * 64 + c] * inv;
            sp += w * u[c]; sq += w * v[c]; sr += w * b1[c];
        }
        p[tid] = sp; q[tid] = sq; r[tid] = sr;
    }
    __syncthreads();

    const int n3 = tid & 31, og = tid >> 5;
    float nn = 0.f, mk = 0.f, mq = 0.f, mr = 0.f, mb = 0.f;
    #pragma unroll
    for (int i = 0; i < 16; ++i) {
        int o = og + 8 * i;
        float w = Vfc[k * 4096 + tid + 256 * i];
        nn += w * w;
        mk += w * p[o]; mq += w * q[o]; mr += w * r[o]; mb += w * b2[o];
    }
    #pragma unroll
    for (int off = 32; off; off >>= 1) nn += __shfl_xor(nn, off);
    if ((tid & 63) == 0) nnred[tid >> 6] = nn;
    redA[og][n3] = mk; redB[og][n3] = mq; redC[og][n3] = mr; redD[og][n3] = mb;
    __syncthreads();
    if (tid == 0) {
        float s = nnred[0] + nnred[1] + nnred[2] + nnred[3];
        scale_s = gfc[k] * rsqrtf(s);
    }
    __syncthreads();
    if (tid < 32) {
        float smk = 0.f, smq = 0.f, smr = 0.f, smb = 0.f;
        #pragma unroll
        for (int i = 0; i < 8; ++i) {
            smk += redA[i][tid]; smq += redB[i][tid];
            smr += redC[i][tid]; smb += redD[i][tid];
        }
        float scale = scale_s;
        M[tid] = scale * smk;
        float kcp = scale * (smq * T2[tid] + smr * cnt2[tid] + smb);
        #pragma unroll
        for (int off = 16; off; off >>= 1) kcp += __shfl_xor(kcp, off);
        if (tid == 0) Kc_s = kcp + bfc[k];
    }
    __syncthreads();
    if (tid < 32) {
        int b = tid;
        float s = 0.f;
        #pragma unroll
        for (int n = 0; n < 32; ++n) s += M[n] * S2[n * 32 + b];
        out[b * NCLS + k] = s + Kc_s;
    }
}

extern "C" void kernel_launch(void* const* d_in, const int* in_sizes, int n_in,
                              void* d_out, int out_size, void* d_ws, size_t ws_size,
                              hipStream_t stream) {
    const float* x   = (const float*)d_in[0];
    const int* src0  = (const int*)d_in[1];
    const int* dst0  = (const int*)d_in[2];
    const int* src1  = (const int*)d_in[3];
    const int* dst1  = (const int*)d_in[4];
    const int* src2  = (const int*)d_in[5];
    const int* dst2  = (const int*)d_in[6];
    const float* V0  = (const float*)d_in[7];
    const float* g0  = (const float*)d_in[8];
    const float* b0  = (const float*)d_in[9];
    const float* V1  = (const float*)d_in[10];
    const float* g1  = (const float*)d_in[11];
    const float* b1  = (const float*)d_in[12];
    const float* V2  = (const float*)d_in[13];
    const float* g2  = (const float*)d_in[14];
    const float* b2  = (const float*)d_in[15];
    const float* Vfc = (const float*)d_in[16];
    const float* gfc = (const float*)d_in[17];
    const float* bfc = (const float*)d_in[18];

    char* ws = (char*)d_ws;
    _Float16* xt  = (_Float16*)(ws);                 // 12,800,000 B
    int* esrc     = (int*)(ws + 12800000);           // 8,192,000 B
    int* bstart   = (int*)(ws + 20992000);           // 20,480 B
    float* P0p    = (float*)(ws + 21012480);         // 524,288 B
    _Float16* P0h = (_Float16*)(ws + 21536768);      // 65,536 B
    _Float16* S1h = (_Float16*)(ws + 21602304);      // 16,384 B
    float* cnt1   = (float*)(ws + 21618688);         // 1,024 B
    float* S2     = (float*)(ws + 21619712);         // 4,096 B
    float* T2     = (float*)(ws + 21623808);         // 128 B
    float* cnt2   = (float*)(ws + 21623936);         // 128 B

    k_transpose<<<(N0 + 63) / 64, 256, 0, stream>>>(x, (h2*)xt);
    k_partition<<<N1, 256, 0, stream>>>(src0, dst0, esrc, bstart);
    k_gather0s<<<N1 * NB, 128, 0, stream>>>((const h8*)xt, esrc, bstart, P0p);
    k_reduceP<<<(N1 * 32) / 256, 256, 0, stream>>>(P0p, P0h);
    k_gather1<<<N2, 256, 0, stream>>>((const h8*)P0h, src1, dst1, S1h, cnt1);
    k_gather2<<<N3, 256, 0, stream>>>((const h8*)S1h, src2, dst2, cnt1,
                                      S2, cnt2, T2);
    k_out<<<NCLS, 256, 0, stream>>>(V0, g0, b0, V1, g1, b1, V2, g2, b2,
                                    Vfc, gfc, bfc, S2, T2, cnt2, (float*)d_out);
}